// Round 4
// baseline (725.113 us; speedup 1.0000x reference)
//
#include <hip/hip_runtime.h>
#include <hip/hip_fp16.h>

// HashGrid encode: N=524288, L=16, F=2, T=2^19.
// R9 (session R4): request-count attack, fused main.
//  Cross-round evidence (R0/R1/R3): divergent-gather service rate is a
//  constant ~0.25 lines/cy/CU regardless of occupancy (11->59%) and L2
//  residency (resident or thrashing). => Only request COUNT matters; pass
//  splitting only added x re-reads (R3: 363 vs R0: 338). Changes:
//  - one fused main kernel again (x once, out once, 16 levels);
//  - dense levels: 32B-aligned OCT entries (both z-slabs) -> 2 loads but
//    ONE 64B line per level (was 2 lines);
//  - hashed levels: dim-0 prime==1 => i0=(H^x0)&M and i1=(H^(x0+1))&M share
//    the aligned 4-entry 16B group iff (x0&3)!=3 (75% of lanes). One
//    dwordx4 per corner-row covers both x-corners; 25% of lanes issue one
//    extra 8B pair load. 6 -> 5 lines per hashed level.
//  Totals per point: 72 instr / 68 lines -> 62 instr / 56 lines.

#define HG_L     16
#define HG_LOG_T 19
#define HG_T     (1u << HG_LOG_T)
#define HG_N     524288u
#define HP1      2654435761u
#define HP2      805459861u

// dense levels 0..5: resolution {16,22,30,42,58,80} -> S = res+1
#define DS0 17u
#define DS1 23u
#define DS2 31u
#define DS3 43u
#define DS4 59u
#define DS5 81u
#define DOFF0 0u
#define DOFF1 4913u      // +17^3
#define DOFF2 17080u     // +23^3
#define DOFF3 46871u     // +31^3
#define DOFF4 126378u    // +43^3
#define DOFF5 331757u    // +59^3
#define DTOTAL 863198u   // +81^3  cells; 32 B each (oct) = 27.6 MB

// ws layout: [0, 10*T*4) hashed pair tables (levels 6..15, rebased l-6),
//            then oct entries (2 x uint4 per dense cell).
#define TAB_BYTES ((size_t)10u * HG_T * 4u)    // 20.97 MB

#define NB_INTER 5120u                          // (10*T/4)/256
#define NB_OCT   6744u                          // ceil(2*DTOTAL/256)

__device__ __forceinline__ unsigned pack_h2(float f0, float f1) {
    __half2 h = __floats2half2_rn(f0, f1);
    return *reinterpret_cast<unsigned*>(&h);
}

// Fused prep: blocks [0, NB_INTER) interleave hashed levels 6..15 into the
// half2 pair table; blocks [NB_INTER, ..) build dense OCT half-entries
// (one thread = one 16B half: z-slab zh of cell's quad).
__global__ __launch_bounds__(256) void hg_prep(
    const float* __restrict__ hm,   // [L, F, T]
    __half2* __restrict__ wst,      // [10, T] rebased hashed tables
    uint4* __restrict__ oct)        // [DTOTAL*2]
{
    const unsigned bid = blockIdx.x;
    const unsigned M = HG_T - 1u;
    if (bid < NB_INTER) {
        const unsigned u  = (bid * 256u + threadIdx.x) * 4u;  // 0..10*T
        const unsigned l6 = u >> HG_LOG_T;                    // 0..9
        const unsigned t  = u & M;
        const float* base = hm + (size_t)(l6 + 6u) * (2u * HG_T);
        const float4 a = *reinterpret_cast<const float4*>(base + t);          // f=0
        const float4 b = *reinterpret_cast<const float4*>(base + HG_T + t);   // f=1
        uint4 o;
        o.x = pack_h2(a.x, b.x);
        o.y = pack_h2(a.y, b.y);
        o.z = pack_h2(a.z, b.z);
        o.w = pack_h2(a.w, b.w);
        *reinterpret_cast<uint4*>(wst + u) = o;
        return;
    }
    const unsigned j = (bid - NB_INTER) * 256u + threadIdx.x; // 0..2*DTOTAL
    if (j >= 2u * DTOTAL) return;
    const unsigned cell = j >> 1;
    const unsigned zh   = j & 1u;
    unsigned l, S, off;
    if      (cell < DOFF1) { l = 0; S = DS0; off = DOFF0; }
    else if (cell < DOFF2) { l = 1; S = DS1; off = DOFF1; }
    else if (cell < DOFF3) { l = 2; S = DS2; off = DOFF2; }
    else if (cell < DOFF4) { l = 3; S = DS3; off = DOFF3; }
    else if (cell < DOFF5) { l = 4; S = DS4; off = DOFF4; }
    else                   { l = 5; S = DS5; off = DOFF5; }
    const unsigned i  = cell - off;
    const unsigned x  = i % S;
    const unsigned t1 = i / S;
    const unsigned y  = t1 % S;
    const unsigned z  = t1 / S + zh;
    const unsigned hz = z * HP2;
    const unsigned hy0 = y * HP1, hy1 = hy0 + HP1;
    const unsigned i00 = (hy0 ^ hz ^ x) & M;
    const unsigned i10 = (hy0 ^ hz ^ (x + 1u)) & M;
    const unsigned i01 = (hy1 ^ hz ^ x) & M;
    const unsigned i11 = (hy1 ^ hz ^ (x + 1u)) & M;
    const float* b0 = hm + (size_t)l * (2u * HG_T);
    uint4 o;
    o.x = pack_h2(b0[i00], b0[i00 + HG_T]);
    o.y = pack_h2(b0[i10], b0[i10 + HG_T]);
    o.z = pack_h2(b0[i01], b0[i01 + HG_T]);
    o.w = pack_h2(b0[i11], b0[i11 + HG_T]);
    oct[j] = o;
}

__device__ __forceinline__ float2 hfv(unsigned raw) {
    return __half22float2(*reinterpret_cast<const __half2*>(&raw));
}

// select entry k (0..3) of an aligned 4-entry group (VALU cndmask chain)
__device__ __forceinline__ unsigned sel4(const uint4& g, unsigned k) {
    const unsigned lo = (k & 1u) ? g.y : g.x;
    const unsigned hi = (k & 1u) ? g.w : g.z;
    return (k & 2u) ? hi : lo;
}

template <unsigned S, unsigned OFF>
__device__ __forceinline__ float2 enc_dense(
    float px, float py, float pz, float res,
    const uint4* __restrict__ oct)
{
    const float xs0 = px * res, xs1 = py * res, xs2 = pz * res;
    const float fl0 = floorf(xs0), fl1 = floorf(xs1), fl2 = floorf(xs2);
    const float fr0 = xs0 - fl0, fr1 = xs1 - fl1, fr2 = xs2 - fl2;
    const unsigned x0 = (unsigned)fl0;
    const unsigned y0 = (unsigned)fl1;
    const unsigned z0 = (unsigned)fl2;

    const unsigned i = ((z0 * S + y0) * S + x0 + OFF) * 2u;
    const uint4 q0 = oct[i];        // z0 slab quad: v00,v10,v01,v11
    const uint4 q1 = oct[i + 1u];   // z0+1 slab quad (same 64B line)

    const float w0x = 1.0f - fr0, w1x = fr0;
    const float w0y = 1.0f - fr1, w1y = fr1;
    const float w0z = 1.0f - fr2, w1z = fr2;

    const float2 a00 = hfv(q0.x), a10 = hfv(q0.y), a01 = hfv(q0.z), a11 = hfv(q0.w);
    const float2 b00 = hfv(q1.x), b10 = hfv(q1.y), b01 = hfv(q1.z), b11 = hfv(q1.w);

    const float s0x = w0y * (w0x * a00.x + w1x * a10.x) + w1y * (w0x * a01.x + w1x * a11.x);
    const float s0y = w0y * (w0x * a00.y + w1x * a10.y) + w1y * (w0x * a01.y + w1x * a11.y);
    const float s1x = w0y * (w0x * b00.x + w1x * b10.x) + w1y * (w0x * b01.x + w1x * b11.x);
    const float s1y = w0y * (w0x * b00.y + w1x * b10.y) + w1y * (w0x * b01.y + w1x * b11.y);

    return make_float2(w0z * s0x + w1z * s1x, w0z * s0y + w1z * s1y);
}

__device__ __forceinline__ float2 enc_hash(
    float px, float py, float pz, float res,
    const uint2* __restrict__ tab2)   // level's table as aligned pairs
{
    const float xs0 = px * res, xs1 = py * res, xs2 = pz * res;
    const float fl0 = floorf(xs0), fl1 = floorf(xs1), fl2 = floorf(xs2);
    const float fr0 = xs0 - fl0, fr1 = xs1 - fl1, fr2 = xs2 - fl2;
    const unsigned x0 = (unsigned)fl0;
    const unsigned y0 = (unsigned)fl1;
    const unsigned z0 = (unsigned)fl2;
    const unsigned M = HG_T - 1u;
    const uint4* tab4 = reinterpret_cast<const uint4*>(tab2);

    const unsigned hy0 = y0 * HP1, hy1 = hy0 + HP1;
    const unsigned hz0 = z0 * HP2, hz1 = hz0 + HP2;
    const unsigned H0 = hy0 ^ hz0;
    const unsigned H1 = hy1 ^ hz0;
    const unsigned H2 = hy0 ^ hz1;
    const unsigned H3 = hy1 ^ hz1;
    const unsigned x1 = x0 + 1u;

    const unsigned i00 = (H0 ^ x0) & M, i01 = (H0 ^ x1) & M;
    const unsigned i10 = (H1 ^ x0) & M, i11 = (H1 ^ x1) & M;
    const unsigned i20 = (H2 ^ x0) & M, i21 = (H2 ^ x1) & M;
    const unsigned i30 = (H3 ^ x0) & M, i31 = (H3 ^ x1) & M;

    // one 16B group load per corner-row covers BOTH x corners when
    // (x0&3)!=3 (i0 and i1 share the aligned-4 group).
    const uint4 g0 = tab4[i00 >> 2];
    const uint4 g1 = tab4[i10 >> 2];
    const uint4 g2 = tab4[i20 >> 2];
    const uint4 g3 = tab4[i30 >> 2];

    unsigned c00 = sel4(g0, i00 & 3u), c01 = sel4(g0, i01 & 3u);
    unsigned c10 = sel4(g1, i10 & 3u), c11 = sel4(g1, i11 & 3u);
    unsigned c20 = sel4(g2, i20 & 3u), c21 = sel4(g2, i21 & 3u);
    unsigned c30 = sel4(g3, i30 & 3u), c31 = sel4(g3, i31 & 3u);

    if ((x0 & 3u) == 3u) {   // x1 crossed the group (25% of lanes): reload
        { const uint2 p = tab2[i01 >> 1]; c01 = (i01 & 1u) ? p.y : p.x; }
        { const uint2 p = tab2[i11 >> 1]; c11 = (i11 & 1u) ? p.y : p.x; }
        { const uint2 p = tab2[i21 >> 1]; c21 = (i21 & 1u) ? p.y : p.x; }
        { const uint2 p = tab2[i31 >> 1]; c31 = (i31 & 1u) ? p.y : p.x; }
    }

    const float w0x = 1.0f - fr0, w1x = fr0;
    const float w00 = (1.0f - fr1) * (1.0f - fr2);
    const float w10 = fr1 * (1.0f - fr2);
    const float w01 = (1.0f - fr1) * fr2;
    const float w11 = fr1 * fr2;

    float ax = 0.0f, ay = 0.0f;
    { const float2 v0 = hfv(c00), v1 = hfv(c01);
      ax += w00 * (w0x * v0.x + w1x * v1.x);
      ay += w00 * (w0x * v0.y + w1x * v1.y); }
    { const float2 v0 = hfv(c10), v1 = hfv(c11);
      ax += w10 * (w0x * v0.x + w1x * v1.x);
      ay += w10 * (w0x * v0.y + w1x * v1.y); }
    { const float2 v0 = hfv(c20), v1 = hfv(c21);
      ax += w01 * (w0x * v0.x + w1x * v1.x);
      ay += w01 * (w0x * v0.y + w1x * v1.y); }
    { const float2 v0 = hfv(c30), v1 = hfv(c31);
      ax += w11 * (w0x * v0.x + w1x * v1.x);
      ay += w11 * (w0x * v0.y + w1x * v1.y); }
    return make_float2(ax, ay);
}

__global__ __launch_bounds__(256, 4) void hg_main(
    const float* __restrict__ x,          // [N, 3]
    const uint2* __restrict__ tab2,       // hashed pair table [10*T/2], rebased
    const uint4* __restrict__ oct,        // dense oct lattices [DTOTAL*2]
    const float* __restrict__ resolution, // [L]
    float*       __restrict__ out)        // [N, 32]
{
    const unsigned p = blockIdx.x * 256u + threadIdx.x;
    const float ax = x[p * 3 + 0], ay = x[p * 3 + 1], az = x[p * 3 + 2];

    float2 A[16];
    A[0] = enc_dense<DS0, DOFF0>(ax, ay, az, resolution[0], oct);
    A[1] = enc_dense<DS1, DOFF1>(ax, ay, az, resolution[1], oct);
    A[2] = enc_dense<DS2, DOFF2>(ax, ay, az, resolution[2], oct);
    A[3] = enc_dense<DS3, DOFF3>(ax, ay, az, resolution[3], oct);
    A[4] = enc_dense<DS4, DOFF4>(ax, ay, az, resolution[4], oct);
    A[5] = enc_dense<DS5, DOFF5>(ax, ay, az, resolution[5], oct);
#pragma unroll
    for (int l = 6; l < 16; ++l) {
        A[l] = enc_hash(ax, ay, az, resolution[l],
                        tab2 + (size_t)(l - 6) * (HG_T / 2u));
    }

    float4* d = reinterpret_cast<float4*>(out + (size_t)p * 32u);
#pragma unroll
    for (int k = 0; k < 8; ++k) {
        d[k] = make_float4(A[2 * k].x, A[2 * k].y, A[2 * k + 1].x, A[2 * k + 1].y);
    }
}

extern "C" void kernel_launch(void* const* d_in, const int* in_sizes, int n_in,
                              void* d_out, int out_size, void* d_ws, size_t ws_size,
                              hipStream_t stream) {
    const float* x          = (const float*)d_in[0];
    const float* hashmap    = (const float*)d_in[1];
    const float* resolution = (const float*)d_in[2];
    float* out              = (float*)d_out;

    __half2* wst = (__half2*)d_ws;                         // 20.97 MB hashed tables
    uint4*   oct = (uint4*)((char*)d_ws + TAB_BYTES);      // 27.6 MB oct lattices

    hipLaunchKernelGGL(hg_prep, dim3(NB_INTER + NB_OCT), dim3(256), 0, stream,
                       hashmap, wst, oct);

    hipLaunchKernelGGL(hg_main, dim3(HG_N / 256u), dim3(256), 0, stream,
                       x, (const uint2*)d_ws, oct, resolution, out);
}

// Round 5
// 446.731 us; speedup vs baseline: 1.6232x; 1.6232x over previous
//
#include <hip/hip_runtime.h>
#include <hip/hip_fp16.h>

// HashGrid encode: N=524288, L=16, F=2, T=2^19.
// R10 (session R5): R4's request-count attack, spill-proof.
//  R4 post-mortem: float2 A[16] held live across all 16 levels forced the
//  allocator to the 64-reg step WITH scratch spills: FETCH 1.45GB / WRITE
//  883MB (output is 64MB) = ~1.7KB/point of scratch round-trip. 610us.
//  Fix (structure only, same memory layout as R4):
//  - store each level pair IMMEDIATELY (one float4 per 2 levels; R3's
//    pair kernels ran at 24 VGPR with this shape);
//  - hashed pair loop is '#pragma unroll 1' so the compiler cannot hoist
//    all group loads into flight;
//  - __launch_bounds__(256,4): 128-reg cap, 16 waves/CU (R3: >=40% occ
//    already saturates the divergent-gather service rate).
//  Kept from R4: dense OCT entries (1 line/level), hashed aligned-4 group
//  loads (5 lines/level). ~56 lines/pt vs R0's 68.

#define HG_L     16
#define HG_LOG_T 19
#define HG_T     (1u << HG_LOG_T)
#define HG_N     524288u
#define HP1      2654435761u
#define HP2      805459861u

// dense levels 0..5: resolution {16,22,30,42,58,80} -> S = res+1
#define DS0 17u
#define DS1 23u
#define DS2 31u
#define DS3 43u
#define DS4 59u
#define DS5 81u
#define DOFF0 0u
#define DOFF1 4913u      // +17^3
#define DOFF2 17080u     // +23^3
#define DOFF3 46871u     // +31^3
#define DOFF4 126378u    // +43^3
#define DOFF5 331757u    // +59^3
#define DTOTAL 863198u   // +81^3  cells; 32 B each (oct) = 27.6 MB

// ws layout: [0, 10*T*4) hashed pair tables (levels 6..15, rebased l-6),
//            then oct entries (2 x uint4 per dense cell).
#define TAB_BYTES ((size_t)10u * HG_T * 4u)    // 20.97 MB

#define NB_INTER 5120u                          // (10*T/4)/256
#define NB_OCT   6744u                          // ceil(2*DTOTAL/256)

__device__ __forceinline__ unsigned pack_h2(float f0, float f1) {
    __half2 h = __floats2half2_rn(f0, f1);
    return *reinterpret_cast<unsigned*>(&h);
}

// Fused prep: blocks [0, NB_INTER) interleave hashed levels 6..15 into the
// half2 pair table; blocks [NB_INTER, ..) build dense OCT half-entries
// (one thread = one 16B half: z-slab zh of cell's quad).
__global__ __launch_bounds__(256) void hg_prep(
    const float* __restrict__ hm,   // [L, F, T]
    __half2* __restrict__ wst,      // [10, T] rebased hashed tables
    uint4* __restrict__ oct)        // [DTOTAL*2]
{
    const unsigned bid = blockIdx.x;
    const unsigned M = HG_T - 1u;
    if (bid < NB_INTER) {
        const unsigned u  = (bid * 256u + threadIdx.x) * 4u;  // 0..10*T
        const unsigned l6 = u >> HG_LOG_T;                    // 0..9
        const unsigned t  = u & M;
        const float* base = hm + (size_t)(l6 + 6u) * (2u * HG_T);
        const float4 a = *reinterpret_cast<const float4*>(base + t);          // f=0
        const float4 b = *reinterpret_cast<const float4*>(base + HG_T + t);   // f=1
        uint4 o;
        o.x = pack_h2(a.x, b.x);
        o.y = pack_h2(a.y, b.y);
        o.z = pack_h2(a.z, b.z);
        o.w = pack_h2(a.w, b.w);
        *reinterpret_cast<uint4*>(wst + u) = o;
        return;
    }
    const unsigned j = (bid - NB_INTER) * 256u + threadIdx.x; // 0..2*DTOTAL
    if (j >= 2u * DTOTAL) return;
    const unsigned cell = j >> 1;
    const unsigned zh   = j & 1u;
    unsigned l, S, off;
    if      (cell < DOFF1) { l = 0; S = DS0; off = DOFF0; }
    else if (cell < DOFF2) { l = 1; S = DS1; off = DOFF1; }
    else if (cell < DOFF3) { l = 2; S = DS2; off = DOFF2; }
    else if (cell < DOFF4) { l = 3; S = DS3; off = DOFF3; }
    else if (cell < DOFF5) { l = 4; S = DS4; off = DOFF4; }
    else                   { l = 5; S = DS5; off = DOFF5; }
    const unsigned i  = cell - off;
    const unsigned x  = i % S;
    const unsigned t1 = i / S;
    const unsigned y  = t1 % S;
    const unsigned z  = t1 / S + zh;
    const unsigned hz = z * HP2;
    const unsigned hy0 = y * HP1, hy1 = hy0 + HP1;
    const unsigned i00 = (hy0 ^ hz ^ x) & M;
    const unsigned i10 = (hy0 ^ hz ^ (x + 1u)) & M;
    const unsigned i01 = (hy1 ^ hz ^ x) & M;
    const unsigned i11 = (hy1 ^ hz ^ (x + 1u)) & M;
    const float* b0 = hm + (size_t)l * (2u * HG_T);
    uint4 o;
    o.x = pack_h2(b0[i00], b0[i00 + HG_T]);
    o.y = pack_h2(b0[i10], b0[i10 + HG_T]);
    o.z = pack_h2(b0[i01], b0[i01 + HG_T]);
    o.w = pack_h2(b0[i11], b0[i11 + HG_T]);
    oct[j] = o;
}

__device__ __forceinline__ float2 hfv(unsigned raw) {
    return __half22float2(*reinterpret_cast<const __half2*>(&raw));
}

// select entry k (0..3) of an aligned 4-entry group (VALU cndmask chain)
__device__ __forceinline__ unsigned sel4(const uint4& g, unsigned k) {
    const unsigned lo = (k & 1u) ? g.y : g.x;
    const unsigned hi = (k & 1u) ? g.w : g.z;
    return (k & 2u) ? hi : lo;
}

template <unsigned S, unsigned OFF>
__device__ __forceinline__ float2 enc_dense(
    float px, float py, float pz, float res,
    const uint4* __restrict__ oct)
{
    const float xs0 = px * res, xs1 = py * res, xs2 = pz * res;
    const float fl0 = floorf(xs0), fl1 = floorf(xs1), fl2 = floorf(xs2);
    const float fr0 = xs0 - fl0, fr1 = xs1 - fl1, fr2 = xs2 - fl2;
    const unsigned x0 = (unsigned)fl0;
    const unsigned y0 = (unsigned)fl1;
    const unsigned z0 = (unsigned)fl2;

    const unsigned i = ((z0 * S + y0) * S + x0 + OFF) * 2u;
    const uint4 q0 = oct[i];        // z0 slab quad: v00,v10,v01,v11
    const uint4 q1 = oct[i + 1u];   // z0+1 slab quad (same 64B line)

    const float w0x = 1.0f - fr0, w1x = fr0;
    const float w0y = 1.0f - fr1, w1y = fr1;
    const float w0z = 1.0f - fr2, w1z = fr2;

    const float2 a00 = hfv(q0.x), a10 = hfv(q0.y), a01 = hfv(q0.z), a11 = hfv(q0.w);
    const float2 b00 = hfv(q1.x), b10 = hfv(q1.y), b01 = hfv(q1.z), b11 = hfv(q1.w);

    const float s0x = w0y * (w0x * a00.x + w1x * a10.x) + w1y * (w0x * a01.x + w1x * a11.x);
    const float s0y = w0y * (w0x * a00.y + w1x * a10.y) + w1y * (w0x * a01.y + w1x * a11.y);
    const float s1x = w0y * (w0x * b00.x + w1x * b10.x) + w1y * (w0x * b01.x + w1x * b11.x);
    const float s1y = w0y * (w0x * b00.y + w1x * b10.y) + w1y * (w0x * b01.y + w1x * b11.y);

    return make_float2(w0z * s0x + w1z * s1x, w0z * s0y + w1z * s1y);
}

__device__ __forceinline__ float2 enc_hash(
    float px, float py, float pz, float res,
    const uint2* __restrict__ tab2)   // level's table as aligned pairs
{
    const float xs0 = px * res, xs1 = py * res, xs2 = pz * res;
    const float fl0 = floorf(xs0), fl1 = floorf(xs1), fl2 = floorf(xs2);
    const float fr0 = xs0 - fl0, fr1 = xs1 - fl1, fr2 = xs2 - fl2;
    const unsigned x0 = (unsigned)fl0;
    const unsigned y0 = (unsigned)fl1;
    const unsigned z0 = (unsigned)fl2;
    const unsigned M = HG_T - 1u;
    const uint4* tab4 = reinterpret_cast<const uint4*>(tab2);

    const unsigned hy0 = y0 * HP1, hy1 = hy0 + HP1;
    const unsigned hz0 = z0 * HP2, hz1 = hz0 + HP2;
    const unsigned H0 = hy0 ^ hz0;
    const unsigned H1 = hy1 ^ hz0;
    const unsigned H2 = hy0 ^ hz1;
    const unsigned H3 = hy1 ^ hz1;
    const unsigned x1 = x0 + 1u;

    const unsigned i00 = (H0 ^ x0) & M, i01 = (H0 ^ x1) & M;
    const unsigned i10 = (H1 ^ x0) & M, i11 = (H1 ^ x1) & M;
    const unsigned i20 = (H2 ^ x0) & M, i21 = (H2 ^ x1) & M;
    const unsigned i30 = (H3 ^ x0) & M, i31 = (H3 ^ x1) & M;

    // one 16B group load per corner-row covers BOTH x corners when
    // (x0&3)!=3 (i0 and i1 share the aligned-4 group).
    const uint4 g0 = tab4[i00 >> 2];
    const uint4 g1 = tab4[i10 >> 2];
    const uint4 g2 = tab4[i20 >> 2];
    const uint4 g3 = tab4[i30 >> 2];

    unsigned c00 = sel4(g0, i00 & 3u), c01 = sel4(g0, i01 & 3u);
    unsigned c10 = sel4(g1, i10 & 3u), c11 = sel4(g1, i11 & 3u);
    unsigned c20 = sel4(g2, i20 & 3u), c21 = sel4(g2, i21 & 3u);
    unsigned c30 = sel4(g3, i30 & 3u), c31 = sel4(g3, i31 & 3u);

    if ((x0 & 3u) == 3u) {   // x1 crossed the group (25% of lanes): reload
        { const uint2 p = tab2[i01 >> 1]; c01 = (i01 & 1u) ? p.y : p.x; }
        { const uint2 p = tab2[i11 >> 1]; c11 = (i11 & 1u) ? p.y : p.x; }
        { const uint2 p = tab2[i21 >> 1]; c21 = (i21 & 1u) ? p.y : p.x; }
        { const uint2 p = tab2[i31 >> 1]; c31 = (i31 & 1u) ? p.y : p.x; }
    }

    const float w0x = 1.0f - fr0, w1x = fr0;
    const float w00 = (1.0f - fr1) * (1.0f - fr2);
    const float w10 = fr1 * (1.0f - fr2);
    const float w01 = (1.0f - fr1) * fr2;
    const float w11 = fr1 * fr2;

    float ax = 0.0f, ay = 0.0f;
    { const float2 v0 = hfv(c00), v1 = hfv(c01);
      ax += w00 * (w0x * v0.x + w1x * v1.x);
      ay += w00 * (w0x * v0.y + w1x * v1.y); }
    { const float2 v0 = hfv(c10), v1 = hfv(c11);
      ax += w10 * (w0x * v0.x + w1x * v1.x);
      ay += w10 * (w0x * v0.y + w1x * v1.y); }
    { const float2 v0 = hfv(c20), v1 = hfv(c21);
      ax += w01 * (w0x * v0.x + w1x * v1.x);
      ay += w01 * (w0x * v0.y + w1x * v1.y); }
    { const float2 v0 = hfv(c30), v1 = hfv(c31);
      ax += w11 * (w0x * v0.x + w1x * v1.x);
      ay += w11 * (w0x * v0.y + w1x * v1.y); }
    return make_float2(ax, ay);
}

__global__ __launch_bounds__(256, 4) void hg_main(
    const float* __restrict__ x,          // [N, 3]
    const uint2* __restrict__ tab2,       // hashed pair table [10*T/2], rebased
    const uint4* __restrict__ oct,        // dense oct lattices [DTOTAL*2]
    const float* __restrict__ resolution, // [L]
    float*       __restrict__ out)        // [N, 32]
{
    const unsigned p = blockIdx.x * 256u + threadIdx.x;
    const float ax = x[p * 3 + 0], ay = x[p * 3 + 1], az = x[p * 3 + 2];
    float4* d = reinterpret_cast<float4*>(out + (size_t)p * 32u);

    // dense levels: store each pair immediately (no long-lived array)
    {
        const float2 a = enc_dense<DS0, DOFF0>(ax, ay, az, resolution[0], oct);
        const float2 b = enc_dense<DS1, DOFF1>(ax, ay, az, resolution[1], oct);
        d[0] = make_float4(a.x, a.y, b.x, b.y);
    }
    {
        const float2 a = enc_dense<DS2, DOFF2>(ax, ay, az, resolution[2], oct);
        const float2 b = enc_dense<DS3, DOFF3>(ax, ay, az, resolution[3], oct);
        d[1] = make_float4(a.x, a.y, b.x, b.y);
    }
    {
        const float2 a = enc_dense<DS4, DOFF4>(ax, ay, az, resolution[4], oct);
        const float2 b = enc_dense<DS5, DOFF5>(ax, ay, az, resolution[5], oct);
        d[2] = make_float4(a.x, a.y, b.x, b.y);
    }

    // hashed levels: one pair per iteration, NOT unrolled -> bounded regs
#pragma unroll 1
    for (int pr = 0; pr < 5; ++pr) {
        const int l0 = 6 + 2 * pr;
        const float2 a = enc_hash(ax, ay, az, resolution[l0],
                                  tab2 + (size_t)(l0 - 6) * (HG_T / 2u));
        const float2 b = enc_hash(ax, ay, az, resolution[l0 + 1],
                                  tab2 + (size_t)(l0 - 5) * (HG_T / 2u));
        d[3 + pr] = make_float4(a.x, a.y, b.x, b.y);
    }
}

extern "C" void kernel_launch(void* const* d_in, const int* in_sizes, int n_in,
                              void* d_out, int out_size, void* d_ws, size_t ws_size,
                              hipStream_t stream) {
    const float* x          = (const float*)d_in[0];
    const float* hashmap    = (const float*)d_in[1];
    const float* resolution = (const float*)d_in[2];
    float* out              = (float*)d_out;

    __half2* wst = (__half2*)d_ws;                         // 20.97 MB hashed tables
    uint4*   oct = (uint4*)((char*)d_ws + TAB_BYTES);      // 27.6 MB oct lattices

    hipLaunchKernelGGL(hg_prep, dim3(NB_INTER + NB_OCT), dim3(256), 0, stream,
                       hashmap, wst, oct);

    hipLaunchKernelGGL(hg_main, dim3(HG_N / 256u), dim3(256), 0, stream,
                       x, (const uint2*)d_ws, oct, resolution, out);
}

// Round 7
// 347.605 us; speedup vs baseline: 2.0860x; 1.2852x over previous
//
#include <hip/hip_runtime.h>
#include <hip/hip_fp16.h>

// HashGrid encode: N=524288, L=16, F=2, T=2^19.
// R11 resubmit (session R7): pass-sync x per-thread MLP. R6 bench died on
// an infra error (container acquire failed twice) before running; same
// design, byte-identical kernels.
//  Evidence: traffic is minimal only with pass-level level-sync (R3: 57
//  MB/pass = compulsory; R5 fused: +600 MB from level-desync across 27
//  waves/CU -> BW-bound 335 us). Within a pass, time = latency x MLP
//  (R3 1pt/thread: 44 us/pass; R0 proved 2 pts/thread doubles in-flight
//  without spilling).
//  Structure: 8 stream-ordered passes, each 1024 blocks x 256 thr x 2 pts:
//    prep | dense L0-3 (oct 4MB resident) -> d0,d1 | dense L4-5 -> d2 |
//    hash {6,7}..{14,15} (2+2 MB tables = one XCD L2) -> d3..d7.
//  Kept: oct dense entries (1 line/level), aligned-4 hashed group loads
//  (5 lines/level, dim-0 prime==1 trick), immediate stores (no spills).

#define HG_L     16
#define HG_LOG_T 19
#define HG_T     (1u << HG_LOG_T)
#define HG_N     524288u
#define HP1      2654435761u
#define HP2      805459861u

// dense levels 0..5: resolution {16,22,30,42,58,80} -> S = res+1
#define DS0 17u
#define DS1 23u
#define DS2 31u
#define DS3 43u
#define DS4 59u
#define DS5 81u
#define DOFF0 0u
#define DOFF1 4913u      // +17^3
#define DOFF2 17080u     // +23^3
#define DOFF3 46871u     // +31^3
#define DOFF4 126378u    // +43^3
#define DOFF5 331757u    // +59^3
#define DTOTAL 863198u   // +81^3  cells; 32 B each (oct) = 27.6 MB

// ws layout: [0, 10*T*4) hashed pair tables (levels 6..15, rebased l-6),
//            then oct entries (2 x uint4 per dense cell).
#define TAB_BYTES ((size_t)10u * HG_T * 4u)    // 20.97 MB

#define NB_INTER 5120u                          // (10*T/4)/256
#define NB_OCT   6744u                          // ceil(2*DTOTAL/256)

__device__ __forceinline__ unsigned pack_h2(float f0, float f1) {
    __half2 h = __floats2half2_rn(f0, f1);
    return *reinterpret_cast<unsigned*>(&h);
}

// Fused prep: blocks [0, NB_INTER) interleave hashed levels 6..15 into the
// half2 pair table; blocks [NB_INTER, ..) build dense OCT half-entries
// (one thread = one 16B half: z-slab zh of cell's quad).
__global__ __launch_bounds__(256) void hg_prep(
    const float* __restrict__ hm,   // [L, F, T]
    __half2* __restrict__ wst,      // [10, T] rebased hashed tables
    uint4* __restrict__ oct)        // [DTOTAL*2]
{
    const unsigned bid = blockIdx.x;
    const unsigned M = HG_T - 1u;
    if (bid < NB_INTER) {
        const unsigned u  = (bid * 256u + threadIdx.x) * 4u;  // 0..10*T
        const unsigned l6 = u >> HG_LOG_T;                    // 0..9
        const unsigned t  = u & M;
        const float* base = hm + (size_t)(l6 + 6u) * (2u * HG_T);
        const float4 a = *reinterpret_cast<const float4*>(base + t);          // f=0
        const float4 b = *reinterpret_cast<const float4*>(base + HG_T + t);   // f=1
        uint4 o;
        o.x = pack_h2(a.x, b.x);
        o.y = pack_h2(a.y, b.y);
        o.z = pack_h2(a.z, b.z);
        o.w = pack_h2(a.w, b.w);
        *reinterpret_cast<uint4*>(wst + u) = o;
        return;
    }
    const unsigned j = (bid - NB_INTER) * 256u + threadIdx.x; // 0..2*DTOTAL
    if (j >= 2u * DTOTAL) return;
    const unsigned cell = j >> 1;
    const unsigned zh   = j & 1u;
    unsigned l, S, off;
    if      (cell < DOFF1) { l = 0; S = DS0; off = DOFF0; }
    else if (cell < DOFF2) { l = 1; S = DS1; off = DOFF1; }
    else if (cell < DOFF3) { l = 2; S = DS2; off = DOFF2; }
    else if (cell < DOFF4) { l = 3; S = DS3; off = DOFF3; }
    else if (cell < DOFF5) { l = 4; S = DS4; off = DOFF4; }
    else                   { l = 5; S = DS5; off = DOFF5; }
    const unsigned i  = cell - off;
    const unsigned x  = i % S;
    const unsigned t1 = i / S;
    const unsigned y  = t1 % S;
    const unsigned z  = t1 / S + zh;
    const unsigned hz = z * HP2;
    const unsigned hy0 = y * HP1, hy1 = hy0 + HP1;
    const unsigned i00 = (hy0 ^ hz ^ x) & M;
    const unsigned i10 = (hy0 ^ hz ^ (x + 1u)) & M;
    const unsigned i01 = (hy1 ^ hz ^ x) & M;
    const unsigned i11 = (hy1 ^ hz ^ (x + 1u)) & M;
    const float* b0 = hm + (size_t)l * (2u * HG_T);
    uint4 o;
    o.x = pack_h2(b0[i00], b0[i00 + HG_T]);
    o.y = pack_h2(b0[i10], b0[i10 + HG_T]);
    o.z = pack_h2(b0[i01], b0[i01 + HG_T]);
    o.w = pack_h2(b0[i11], b0[i11 + HG_T]);
    oct[j] = o;
}

__device__ __forceinline__ float2 hfv(unsigned raw) {
    return __half22float2(*reinterpret_cast<const __half2*>(&raw));
}

// select entry k (0..3) of an aligned 4-entry group (VALU cndmask chain)
__device__ __forceinline__ unsigned sel4(const uint4& g, unsigned k) {
    const unsigned lo = (k & 1u) ? g.y : g.x;
    const unsigned hi = (k & 1u) ? g.w : g.z;
    return (k & 2u) ? hi : lo;
}

template <unsigned S, unsigned OFF>
__device__ __forceinline__ float2 enc_dense(
    float px, float py, float pz, float res,
    const uint4* __restrict__ oct)
{
    const float xs0 = px * res, xs1 = py * res, xs2 = pz * res;
    const float fl0 = floorf(xs0), fl1 = floorf(xs1), fl2 = floorf(xs2);
    const float fr0 = xs0 - fl0, fr1 = xs1 - fl1, fr2 = xs2 - fl2;
    const unsigned x0 = (unsigned)fl0;
    const unsigned y0 = (unsigned)fl1;
    const unsigned z0 = (unsigned)fl2;

    const unsigned i = ((z0 * S + y0) * S + x0 + OFF) * 2u;
    const uint4 q0 = oct[i];        // z0 slab quad: v00,v10,v01,v11
    const uint4 q1 = oct[i + 1u];   // z0+1 slab quad (same 64B line)

    const float w0x = 1.0f - fr0, w1x = fr0;
    const float w0y = 1.0f - fr1, w1y = fr1;
    const float w0z = 1.0f - fr2, w1z = fr2;

    const float2 a00 = hfv(q0.x), a10 = hfv(q0.y), a01 = hfv(q0.z), a11 = hfv(q0.w);
    const float2 b00 = hfv(q1.x), b10 = hfv(q1.y), b01 = hfv(q1.z), b11 = hfv(q1.w);

    const float s0x = w0y * (w0x * a00.x + w1x * a10.x) + w1y * (w0x * a01.x + w1x * a11.x);
    const float s0y = w0y * (w0x * a00.y + w1x * a10.y) + w1y * (w0x * a01.y + w1x * a11.y);
    const float s1x = w0y * (w0x * b00.x + w1x * b10.x) + w1y * (w0x * b01.x + w1x * b11.x);
    const float s1y = w0y * (w0x * b00.y + w1x * b10.y) + w1y * (w0x * b01.y + w1x * b11.y);

    return make_float2(w0z * s0x + w1z * s1x, w0z * s0y + w1z * s1y);
}

__device__ __forceinline__ float2 enc_hash(
    float px, float py, float pz, float res,
    const uint2* __restrict__ tab2)   // level's table as aligned pairs
{
    const float xs0 = px * res, xs1 = py * res, xs2 = pz * res;
    const float fl0 = floorf(xs0), fl1 = floorf(xs1), fl2 = floorf(xs2);
    const float fr0 = xs0 - fl0, fr1 = xs1 - fl1, fr2 = xs2 - fl2;
    const unsigned x0 = (unsigned)fl0;
    const unsigned y0 = (unsigned)fl1;
    const unsigned z0 = (unsigned)fl2;
    const unsigned M = HG_T - 1u;
    const uint4* tab4 = reinterpret_cast<const uint4*>(tab2);

    const unsigned hy0 = y0 * HP1, hy1 = hy0 + HP1;
    const unsigned hz0 = z0 * HP2, hz1 = hz0 + HP2;
    const unsigned H0 = hy0 ^ hz0;
    const unsigned H1 = hy1 ^ hz0;
    const unsigned H2 = hy0 ^ hz1;
    const unsigned H3 = hy1 ^ hz1;
    const unsigned x1 = x0 + 1u;

    const unsigned i00 = (H0 ^ x0) & M, i01 = (H0 ^ x1) & M;
    const unsigned i10 = (H1 ^ x0) & M, i11 = (H1 ^ x1) & M;
    const unsigned i20 = (H2 ^ x0) & M, i21 = (H2 ^ x1) & M;
    const unsigned i30 = (H3 ^ x0) & M, i31 = (H3 ^ x1) & M;

    // one 16B group load per corner-row covers BOTH x corners when
    // (x0&3)!=3 (i0 and i1 share the aligned-4 group).
    const uint4 g0 = tab4[i00 >> 2];
    const uint4 g1 = tab4[i10 >> 2];
    const uint4 g2 = tab4[i20 >> 2];
    const uint4 g3 = tab4[i30 >> 2];

    unsigned c00 = sel4(g0, i00 & 3u), c01 = sel4(g0, i01 & 3u);
    unsigned c10 = sel4(g1, i10 & 3u), c11 = sel4(g1, i11 & 3u);
    unsigned c20 = sel4(g2, i20 & 3u), c21 = sel4(g2, i21 & 3u);
    unsigned c30 = sel4(g3, i30 & 3u), c31 = sel4(g3, i31 & 3u);

    if ((x0 & 3u) == 3u) {   // x1 crossed the group (25% of lanes): reload
        { const uint2 p = tab2[i01 >> 1]; c01 = (i01 & 1u) ? p.y : p.x; }
        { const uint2 p = tab2[i11 >> 1]; c11 = (i11 & 1u) ? p.y : p.x; }
        { const uint2 p = tab2[i21 >> 1]; c21 = (i21 & 1u) ? p.y : p.x; }
        { const uint2 p = tab2[i31 >> 1]; c31 = (i31 & 1u) ? p.y : p.x; }
    }

    const float w0x = 1.0f - fr0, w1x = fr0;
    const float w00 = (1.0f - fr1) * (1.0f - fr2);
    const float w10 = fr1 * (1.0f - fr2);
    const float w01 = (1.0f - fr1) * fr2;
    const float w11 = fr1 * fr2;

    float ax = 0.0f, ay = 0.0f;
    { const float2 v0 = hfv(c00), v1 = hfv(c01);
      ax += w00 * (w0x * v0.x + w1x * v1.x);
      ay += w00 * (w0x * v0.y + w1x * v1.y); }
    { const float2 v0 = hfv(c10), v1 = hfv(c11);
      ax += w10 * (w0x * v0.x + w1x * v1.x);
      ay += w10 * (w0x * v0.y + w1x * v1.y); }
    { const float2 v0 = hfv(c20), v1 = hfv(c21);
      ax += w01 * (w0x * v0.x + w1x * v1.x);
      ay += w01 * (w0x * v0.y + w1x * v1.y); }
    { const float2 v0 = hfv(c30), v1 = hfv(c31);
      ax += w11 * (w0x * v0.x + w1x * v1.x);
      ay += w11 * (w0x * v0.y + w1x * v1.y); }
    return make_float2(ax, ay);
}

// Pass: dense levels 0..3 -> d0,d1. Oct region 4.06 MB (L2-resident).
__global__ __launch_bounds__(256, 4) void hg_d01(
    const float* __restrict__ x,
    const uint4* __restrict__ oct,
    const float* __restrict__ resolution,
    float*       __restrict__ out)
{
    const unsigned tid = threadIdx.x;
    const unsigned p0 = blockIdx.x * 512u + tid;
    const unsigned p1 = p0 + 256u;
    const float ax0 = x[p0 * 3 + 0], ay0 = x[p0 * 3 + 1], az0 = x[p0 * 3 + 2];
    const float ax1 = x[p1 * 3 + 0], ay1 = x[p1 * 3 + 1], az1 = x[p1 * 3 + 2];
    const float r0 = resolution[0], r1 = resolution[1];
    const float r2 = resolution[2], r3 = resolution[3];

    const float2 a0 = enc_dense<DS0, DOFF0>(ax0, ay0, az0, r0, oct);
    const float2 b0 = enc_dense<DS1, DOFF1>(ax0, ay0, az0, r1, oct);
    const float2 c0 = enc_dense<DS2, DOFF2>(ax0, ay0, az0, r2, oct);
    const float2 e0 = enc_dense<DS3, DOFF3>(ax0, ay0, az0, r3, oct);
    const float2 a1 = enc_dense<DS0, DOFF0>(ax1, ay1, az1, r0, oct);
    const float2 b1 = enc_dense<DS1, DOFF1>(ax1, ay1, az1, r1, oct);
    const float2 c1 = enc_dense<DS2, DOFF2>(ax1, ay1, az1, r2, oct);
    const float2 e1 = enc_dense<DS3, DOFF3>(ax1, ay1, az1, r3, oct);

    float4* d0 = reinterpret_cast<float4*>(out + (size_t)p0 * 32u);
    float4* d1 = reinterpret_cast<float4*>(out + (size_t)p1 * 32u);
    d0[0] = make_float4(a0.x, a0.y, b0.x, b0.y);
    d0[1] = make_float4(c0.x, c0.y, e0.x, e0.y);
    d1[0] = make_float4(a1.x, a1.y, b1.x, b1.y);
    d1[1] = make_float4(c1.x, c1.y, e1.x, e1.y);
}

// Pass: dense levels 4..5 -> d2. Oct region 23.5 MB (streams).
__global__ __launch_bounds__(256, 4) void hg_d2(
    const float* __restrict__ x,
    const uint4* __restrict__ oct,
    const float* __restrict__ resolution,
    float*       __restrict__ out)
{
    const unsigned tid = threadIdx.x;
    const unsigned p0 = blockIdx.x * 512u + tid;
    const unsigned p1 = p0 + 256u;
    const float ax0 = x[p0 * 3 + 0], ay0 = x[p0 * 3 + 1], az0 = x[p0 * 3 + 2];
    const float ax1 = x[p1 * 3 + 0], ay1 = x[p1 * 3 + 1], az1 = x[p1 * 3 + 2];
    const float r4 = resolution[4], r5 = resolution[5];

    const float2 a0 = enc_dense<DS4, DOFF4>(ax0, ay0, az0, r4, oct);
    const float2 b0 = enc_dense<DS5, DOFF5>(ax0, ay0, az0, r5, oct);
    const float2 a1 = enc_dense<DS4, DOFF4>(ax1, ay1, az1, r4, oct);
    const float2 b1 = enc_dense<DS5, DOFF5>(ax1, ay1, az1, r5, oct);

    reinterpret_cast<float4*>(out + (size_t)p0 * 32u)[2] =
        make_float4(a0.x, a0.y, b0.x, b0.y);
    reinterpret_cast<float4*>(out + (size_t)p1 * 32u)[2] =
        make_float4(a1.x, a1.y, b1.x, b1.y);
}

// Pass: hashed level pair {L0, L0+1} -> d[3+(L0-6)/2]. 2+2 MB = one XCD L2.
template <int L0>
__global__ __launch_bounds__(256, 4) void hg_hpass(
    const float* __restrict__ x,
    const uint2* __restrict__ tab2,
    const float* __restrict__ resolution,
    float*       __restrict__ out)
{
    const unsigned tid = threadIdx.x;
    const unsigned p0 = blockIdx.x * 512u + tid;
    const unsigned p1 = p0 + 256u;
    const float ax0 = x[p0 * 3 + 0], ay0 = x[p0 * 3 + 1], az0 = x[p0 * 3 + 2];
    const float ax1 = x[p1 * 3 + 0], ay1 = x[p1 * 3 + 1], az1 = x[p1 * 3 + 2];
    const uint2* t0 = tab2 + (size_t)(L0 - 6) * (HG_T / 2u);
    const uint2* t1 = tab2 + (size_t)(L0 - 5) * (HG_T / 2u);
    const float r0 = resolution[L0], r1 = resolution[L0 + 1];

    const float2 a0 = enc_hash(ax0, ay0, az0, r0, t0);
    const float2 b0 = enc_hash(ax0, ay0, az0, r1, t1);
    const float2 a1 = enc_hash(ax1, ay1, az1, r0, t0);
    const float2 b1 = enc_hash(ax1, ay1, az1, r1, t1);

    reinterpret_cast<float4*>(out + (size_t)p0 * 32u)[3 + (L0 - 6) / 2] =
        make_float4(a0.x, a0.y, b0.x, b0.y);
    reinterpret_cast<float4*>(out + (size_t)p1 * 32u)[3 + (L0 - 6) / 2] =
        make_float4(a1.x, a1.y, b1.x, b1.y);
}

extern "C" void kernel_launch(void* const* d_in, const int* in_sizes, int n_in,
                              void* d_out, int out_size, void* d_ws, size_t ws_size,
                              hipStream_t stream) {
    const float* x          = (const float*)d_in[0];
    const float* hashmap    = (const float*)d_in[1];
    const float* resolution = (const float*)d_in[2];
    float* out              = (float*)d_out;

    __half2* wst = (__half2*)d_ws;                         // 20.97 MB hashed tables
    uint4*   oct = (uint4*)((char*)d_ws + TAB_BYTES);      // 27.6 MB oct lattices
    const uint2* tab2 = (const uint2*)d_ws;

    hipLaunchKernelGGL(hg_prep, dim3(NB_INTER + NB_OCT), dim3(256), 0, stream,
                       hashmap, wst, oct);

    const dim3 g(HG_N / 512u), b(256);
    hipLaunchKernelGGL(hg_d01,       g, b, 0, stream, x, oct, resolution, out);
    hipLaunchKernelGGL(hg_d2,        g, b, 0, stream, x, oct, resolution, out);
    hipLaunchKernelGGL(hg_hpass< 6>, g, b, 0, stream, x, tab2, resolution, out);
    hipLaunchKernelGGL(hg_hpass< 8>, g, b, 0, stream, x, tab2, resolution, out);
    hipLaunchKernelGGL(hg_hpass<10>, g, b, 0, stream, x, tab2, resolution, out);
    hipLaunchKernelGGL(hg_hpass<12>, g, b, 0, stream, x, tab2, resolution, out);
    hipLaunchKernelGGL(hg_hpass<14>, g, b, 0, stream, x, tab2, resolution, out);
}